// Round 7
// baseline (85.977 us; speedup 1.0000x reference)
//
#include <hip/hip_runtime.h>
#include <hip/hip_bf16.h>
#include <stdint.h>

// SVR polynomial-kernel prediction:
//   out[m] = sum_n alpha[n] * (1 + x_p[m].X[n])^4 + b
// m=16384, n=8192, d=64, all fp32 in/out.
// R7: 2-phase LDS dbuf skeleton from R6 (pre-swizzled Xs in global so
//     global_load_lds stays linear -- rule 21), with:
//   - wave-owns-n-tile: wave w = cols [w*16,w*16+16), all 128 m-rows (MT=8)
//     -> LDS reads per chunk drop 8->2 ds_read_b128 per lane
//   - A (x_p) converted fp32->bf16 in-reg at start (no xbf buffer)
//   - alpha^(1/4) pipelined one chunk ahead (off critical path)
//   - finalize fused: convert inits out[m]=b, svr_main atomicAdds partials
//   - MFMA C-init = a4 so acc = a4*(1+x.X); epilogue 2 VALU/elem

typedef __attribute__((ext_vector_type(8))) short bf16x8;
typedef __attribute__((ext_vector_type(8))) unsigned short ushort8;
typedef __attribute__((ext_vector_type(4))) float f32x4;

#define MM 16384
#define NN 8192
#define DD 64
#define NSPLIT 16          // n-splits
#define CHUNK 64           // n-cols per LDS chunk
#define CHUNKS_PER_BLK 8   // 8192 / (16*64)
#define BM 128             // m-rows per block
#define MT 8               // m-tiles per wave

__device__ __forceinline__ unsigned short f2bf(float f) {
    uint32_t u = __float_as_uint(f);
    uint32_t r = (u + 0x7FFFu + ((u >> 16) & 1u)) >> 16;  // RNE
    return (unsigned short)r;
}

__device__ __forceinline__ void gll16(const void* g, void* l) {
    __builtin_amdgcn_global_load_lds(
        (const __attribute__((address_space(1))) unsigned int*)g,
        (__attribute__((address_space(3))) unsigned int*)l, 16, 0, 0);
}

// X -> Xs swizzled bf16, prescaled by alpha^(1/4):
//   element (n,k) at shorts: (n>>6)*4096 + (n&63)*64 + ((k>>3)^(n&7))*8 + (k&7)
// alpha4f[n] = alpha[n]^(1/4);  out[m] = b  (init for svr_main's atomicAdd)
__global__ void convert_kernel(const float* __restrict__ X,
                               const float* __restrict__ alpha,
                               const float* __restrict__ bbias,
                               unsigned short* __restrict__ Xs,
                               float* __restrict__ alpha4f,
                               float* __restrict__ out) {
    int tid0 = blockIdx.x * blockDim.x + threadIdx.x;   // 0..65535
    if (tid0 < NN) alpha4f[tid0] = sqrtf(sqrtf(alpha[tid0]));
    if (tid0 < MM) out[tid0] = bbias[0];
    int n = tid0 >> 3;
    int slot = tid0 & 7;
    float a4 = sqrtf(sqrtf(alpha[n]));
    float4 va = ((const float4*)X)[n * 16 + slot * 2];
    float4 vb = ((const float4*)X)[n * 16 + slot * 2 + 1];
    ushort8 o;
    o[0] = f2bf(va.x * a4); o[1] = f2bf(va.y * a4);
    o[2] = f2bf(va.z * a4); o[3] = f2bf(va.w * a4);
    o[4] = f2bf(vb.x * a4); o[5] = f2bf(vb.y * a4);
    o[6] = f2bf(vb.z * a4); o[7] = f2bf(vb.w * a4);
    size_t dst = (size_t)(n >> 6) * 4096 + (n & 63) * 64
               + ((slot ^ (n & 7)) * 8);
    *(ushort8*)(Xs + dst) = o;
}

__global__ __launch_bounds__(256) void svr_main(
        const float* __restrict__ xp,
        const unsigned short* __restrict__ Xs,
        const float* __restrict__ alpha4f,
        float* __restrict__ out) {
    __shared__ char smem[16384];          // 2 x 8KB chunk buffers
    const int tid  = threadIdx.x;
    const int lane = tid & 63;
    const int w    = tid >> 6;            // wave 0..3 owns cols [w*16, w*16+16)
    const int r    = lane & 15;           // row-in-tile (A) / col-in-tile (B)
    const int g    = lane >> 4;           // k-slice selector
    const int mgroup = blockIdx.x >> 4;   // 0..127
    const int ns     = blockIdx.x & 15;   // 0..15

    // A fragments: 8 m-tiles x 2 k-slices, fp32->bf16 converted in-reg
    bf16x8 a[MT][2];
#pragma unroll
    for (int mt = 0; mt < MT; ++mt)
#pragma unroll
        for (int ks = 0; ks < 2; ++ks) {
            const float* p = xp + (size_t)(mgroup * BM + mt * 16 + r) * DD
                           + ks * 32 + g * 8;
            float4 v0 = ((const float4*)p)[0];
            float4 v1 = ((const float4*)p)[1];
            ushort8 o;
            o[0] = f2bf(v0.x); o[1] = f2bf(v0.y);
            o[2] = f2bf(v0.z); o[3] = f2bf(v0.w);
            o[4] = f2bf(v1.x); o[5] = f2bf(v1.y);
            o[6] = f2bf(v1.z); o[7] = f2bf(v1.w);
            a[mt][ks] = __builtin_bit_cast(bf16x8, o);
        }

    f32x4 red[MT];
#pragma unroll
    for (int mt = 0; mt < MT; ++mt) red[mt] = (f32x4){0.f, 0.f, 0.f, 0.f};

    const int chunk0 = ns * CHUNKS_PER_BLK;
    const int rr = w * 16 + r;            // chunk-local n index (0..63)

    // prologue: stage chunk0 into buf0; preload alpha for chunk0
    {
        const char* gs = (const char*)Xs + (size_t)chunk0 * 8192 + tid * 16;
        char* lb = smem + w * 1024;
        gll16(gs, lb);
        gll16(gs + 4096, lb + 4096);
    }
    float av_cur = alpha4f[chunk0 * 64 + rr];
    __syncthreads();

    int cur = 0;
#pragma unroll 1
    for (int c = 0; c < CHUNKS_PER_BLK; ++c) {
        float av_nxt;
        if (c + 1 < CHUNKS_PER_BLK) {
            av_nxt = alpha4f[(chunk0 + c + 1) * 64 + rr];
            const char* gs = (const char*)Xs
                           + (size_t)(chunk0 + c + 1) * 8192 + tid * 16;
            char* lb = smem + (cur ^ 1) * 8192 + w * 1024;
            gll16(gs, lb);
            gll16(gs + 4096, lb + 4096);
        }
        // B fragments for this wave's column tile from swizzled LDS
        const char* rowp = smem + cur * 8192 + rr * 128;
        bf16x8 b0 = *(const bf16x8*)(rowp + ((g ^ (rr & 7)) * 16));
        bf16x8 b1 = *(const bf16x8*)(rowp + (((4 + g) ^ (rr & 7)) * 16));
        // acc C-init = a4 so acc_final = a4*(1 + x.X)
        f32x4 acc[MT];
#pragma unroll
        for (int mt = 0; mt < MT; ++mt)
            acc[mt] = (f32x4){av_cur, av_cur, av_cur, av_cur};
#pragma unroll
        for (int mt = 0; mt < MT; ++mt)
            acc[mt] = __builtin_amdgcn_mfma_f32_16x16x32_bf16(a[mt][0], b0, acc[mt], 0, 0, 0);
#pragma unroll
        for (int mt = 0; mt < MT; ++mt)
            acc[mt] = __builtin_amdgcn_mfma_f32_16x16x32_bf16(a[mt][1], b1, acc[mt], 0, 0, 0);
        // epilogue: red += t^4
#pragma unroll
        for (int mt = 0; mt < MT; ++mt)
#pragma unroll
            for (int i = 0; i < 4; ++i) {
                float t = acc[mt][i];
                float t2 = t * t;
                red[mt][i] = fmaf(t2, t2, red[mt][i]);
            }
        __syncthreads();
        cur ^= 1;
        if (c + 1 < CHUNKS_PER_BLK) av_cur = av_nxt;
    }

    // reduce across the 16 column-lanes (r); rows live at g*4+i per m-tile
#pragma unroll
    for (int mt = 0; mt < MT; ++mt)
#pragma unroll
        for (int i = 0; i < 4; ++i) {
            float v = red[mt][i];
            v += __shfl_xor(v, 1);
            v += __shfl_xor(v, 2);
            v += __shfl_xor(v, 4);
            v += __shfl_xor(v, 8);
            red[mt][i] = v;
        }
    if (r == 0) {
#pragma unroll
        for (int mt = 0; mt < MT; ++mt)
#pragma unroll
            for (int i = 0; i < 4; ++i) {
                int row = mgroup * BM + mt * 16 + g * 4 + i;
                atomicAdd(out + row, red[mt][i]);
            }
    }
}

extern "C" void kernel_launch(void* const* d_in, const int* in_sizes, int n_in,
                              void* d_out, int out_size, void* d_ws, size_t ws_size,
                              hipStream_t stream) {
    const float* xp    = (const float*)d_in[0];
    const float* X     = (const float*)d_in[1];
    const float* alpha = (const float*)d_in[2];
    const float* b     = (const float*)d_in[3];
    float* out = (float*)d_out;

    // ws: Xs 1MB | alpha4f 32KB
    unsigned short* Xs = (unsigned short*)d_ws;
    float* alpha4f = (float*)(Xs + (size_t)NN * DD);

    hipLaunchKernelGGL(convert_kernel, dim3(256), dim3(256), 0, stream,
                       X, alpha, b, Xs, alpha4f, out);

    hipLaunchKernelGGL(svr_main, dim3(128 * NSPLIT), dim3(256), 0, stream,
                       xp, Xs, alpha4f, out);
}

// Round 8
// 35.305 us; speedup vs baseline: 2.4352x; 2.4352x over previous
//
#include <hip/hip_runtime.h>
#include <hip/hip_bf16.h>
#include <stdint.h>

// SVR polynomial-kernel prediction:
//   out[m] = sum_n alpha[n] * (1 + x_p[m].X[n])^4 + b
// m=16384, n=8192, d=64, all fp32 in/out.
// R8 = R6 skeleton (proven 36us) with three targeted deltas:
//   1. NSPLIT 16->8: grid 1024 = 4 blocks/CU -> ONE residency round
//      (R7 lesson: 2048 blocks at 5-resident/CU = ragged 2nd round)
//   2. alpha^(1/4) loads pipelined one chunk ahead (off critical path)
//   3. partials+finalize kept (R7 lesson: fused atomicAdd = 64 same-address
//      RMWs/output -> 80us disaster)
// Everything else identical to R6: 4 waves x (2 m-tiles x 4 n-tiles),
// X pre-swizzled in global so global_load_lds is linear (rule 21),
// dbuf LDS, alpha folded via a4-prescaled Xs + a4 C-init, 16x16x32 MFMA.

typedef __attribute__((ext_vector_type(8))) short bf16x8;
typedef __attribute__((ext_vector_type(8))) unsigned short ushort8;
typedef __attribute__((ext_vector_type(4))) float f32x4;

#define MM 16384
#define NN 8192
#define DD 64
#define NSPLIT 8           // n-splits -> partial slices
#define CHUNK 64           // n-cols per LDS chunk
#define CHUNKS_PER_BLK 16  // 8192 / (8*64)
#define BM 128             // m-rows per block

__device__ __forceinline__ unsigned short f2bf(float f) {
    uint32_t u = __float_as_uint(f);
    uint32_t r = (u + 0x7FFFu + ((u >> 16) & 1u)) >> 16;  // RNE
    return (unsigned short)r;
}

__device__ __forceinline__ void gll16(const void* g, void* l) {
    __builtin_amdgcn_global_load_lds(
        (const __attribute__((address_space(1))) unsigned int*)g,
        (__attribute__((address_space(3))) unsigned int*)l, 16, 0, 0);
}

// xp -> xbf linear row-major [16384][64] bf16.
// X  -> Xs swizzled: element (n,k) at shorts:
//   (n>>6)*4096 + (n&63)*64 + ((k>>3) ^ (n&7))*8 + (k&7),  prescaled by a4[n].
// alpha4f[n] = alpha[n]^(1/4).
__global__ void convert_kernel(const float* __restrict__ xp,
                               const float* __restrict__ X,
                               const float* __restrict__ alpha,
                               unsigned short* __restrict__ xbf,
                               unsigned short* __restrict__ Xs,
                               float* __restrict__ alpha4f) {
    const int xp4 = MM * DD / 4;          // 262144 float4 units
    const int xu = NN * DD / 8;           // 65536 16B units
    const int tot = xp4 + xu;
    int tid0 = blockIdx.x * blockDim.x + threadIdx.x;
    if (tid0 < NN) alpha4f[tid0] = sqrtf(sqrtf(alpha[tid0]));
    int stride = gridDim.x * blockDim.x;
    for (int i = tid0; i < tot; i += stride) {
        if (i < xp4) {
            float4 v = ((const float4*)xp)[i];
            ushort4 o;
            o.x = f2bf(v.x); o.y = f2bf(v.y); o.z = f2bf(v.z); o.w = f2bf(v.w);
            *(ushort4*)(xbf + (size_t)i * 4) = o;
        } else {
            int u = i - xp4;
            int n = u >> 3;
            int slot = u & 7;
            float a4 = sqrtf(sqrtf(alpha[n]));
            float4 va = ((const float4*)X)[n * 16 + slot * 2];
            float4 vb = ((const float4*)X)[n * 16 + slot * 2 + 1];
            ushort8 o;
            o[0] = f2bf(va.x * a4); o[1] = f2bf(va.y * a4);
            o[2] = f2bf(va.z * a4); o[3] = f2bf(va.w * a4);
            o[4] = f2bf(vb.x * a4); o[5] = f2bf(vb.y * a4);
            o[6] = f2bf(vb.z * a4); o[7] = f2bf(vb.w * a4);
            size_t dst = (size_t)(n >> 6) * 4096 + (n & 63) * 64
                       + ((slot ^ (n & 7)) * 8);
            *(ushort8*)(Xs + dst) = o;
        }
    }
}

__global__ __launch_bounds__(256) void svr_main(
        const unsigned short* __restrict__ xbf,
        const unsigned short* __restrict__ Xs,
        const float* __restrict__ alpha4f,
        float* __restrict__ partials) {
    __shared__ char smem[16384];          // 2 x 8KB chunk buffers
    const int tid  = threadIdx.x;
    const int lane = tid & 63;
    const int w    = tid >> 6;            // wave 0..3, owns rows [w*32, w*32+32)
    const int r    = lane & 15;           // row-in-tile / col-in-tile
    const int g    = lane >> 4;           // k-slice selector
    const int mgroup = blockIdx.x >> 3;   // 0..127
    const int ns     = blockIdx.x & 7;    // 0..7

    // A fragments: 2 m-tiles x 2 k-slices, regs for whole kernel
    bf16x8 a[2][2];
#pragma unroll
    for (int mt = 0; mt < 2; ++mt)
#pragma unroll
        for (int ks = 0; ks < 2; ++ks)
            a[mt][ks] = *(const bf16x8*)(
                xbf + (size_t)(mgroup * BM + w * 32 + mt * 16 + r) * DD
                    + ks * 32 + g * 8);

    f32x4 red[2];
#pragma unroll
    for (int mt = 0; mt < 2; ++mt) red[mt] = (f32x4){0.f, 0.f, 0.f, 0.f};

    const int chunk0 = ns * CHUNKS_PER_BLK;

    // prologue: stage chunk0 into buf0; preload alpha for chunk0
    {
        const char* gs = (const char*)Xs + (size_t)chunk0 * 8192 + tid * 16;
        char* lb = smem + w * 1024;       // wave-uniform base; +lane*16 implicit
        gll16(gs, lb);
        gll16(gs + 4096, lb + 4096);
    }
    float av4[4];
#pragma unroll
    for (int nt = 0; nt < 4; ++nt)
        av4[nt] = alpha4f[chunk0 * CHUNK + nt * 16 + r];
    __syncthreads();

    int cur = 0;
#pragma unroll 1
    for (int c = 0; c < CHUNKS_PER_BLK; ++c) {
        float av4n[4];
        if (c + 1 < CHUNKS_PER_BLK) {      // stage next chunk into other buffer
            const char* gs = (const char*)Xs
                           + (size_t)(chunk0 + c + 1) * 8192 + tid * 16;
            char* lb = smem + (cur ^ 1) * 8192 + w * 1024;
            gll16(gs, lb);
            gll16(gs + 4096, lb + 4096);
            // pipelined alpha for next chunk (off critical path)
#pragma unroll
            for (int nt = 0; nt < 4; ++nt)
                av4n[nt] = alpha4f[(chunk0 + c + 1) * CHUNK + nt * 16 + r];
        }
        // B fragments from swizzled LDS: rr = nt*16+r, slot = (bh*4+g)^(rr&7)
        bf16x8 b[4][2];
#pragma unroll
        for (int nt = 0; nt < 4; ++nt) {
            const int rr = nt * 16 + r;
            const char* rowp = smem + cur * 8192 + rr * 128;
#pragma unroll
            for (int bh = 0; bh < 2; ++bh) {
                const int slot = (bh * 4 + g) ^ (rr & 7);
                b[nt][bh] = *(const bf16x8*)(rowp + slot * 16);
            }
        }
        // acc C-init = a4 so acc_final = a4*(1 + x.X)
        f32x4 acc[2][4];
#pragma unroll
        for (int mt = 0; mt < 2; ++mt)
#pragma unroll
            for (int nt = 0; nt < 4; ++nt)
                acc[mt][nt] = (f32x4){av4[nt], av4[nt], av4[nt], av4[nt]};
#pragma unroll
        for (int bh = 0; bh < 2; ++bh)
#pragma unroll
            for (int nt = 0; nt < 4; ++nt)
#pragma unroll
                for (int mt = 0; mt < 2; ++mt)
                    acc[mt][nt] = __builtin_amdgcn_mfma_f32_16x16x32_bf16(
                        a[mt][bh], b[nt][bh], acc[mt][nt], 0, 0, 0);
        // epilogue: red += t^4
#pragma unroll
        for (int mt = 0; mt < 2; ++mt)
#pragma unroll
            for (int nt = 0; nt < 4; ++nt)
#pragma unroll
                for (int i = 0; i < 4; ++i) {
                    float t = acc[mt][nt][i];
                    float t2 = t * t;
                    red[mt][i] = fmaf(t2, t2, red[mt][i]);
                }
        __syncthreads();
        cur ^= 1;
        if (c + 1 < CHUNKS_PER_BLK) {
#pragma unroll
            for (int nt = 0; nt < 4; ++nt) av4[nt] = av4n[nt];
        }
    }

    // reduce across the 16 column-lanes (r); rows live at g*4+i per m-tile
#pragma unroll
    for (int mt = 0; mt < 2; ++mt)
#pragma unroll
        for (int i = 0; i < 4; ++i) {
            float v = red[mt][i];
            v += __shfl_xor(v, 1);
            v += __shfl_xor(v, 2);
            v += __shfl_xor(v, 4);
            v += __shfl_xor(v, 8);
            red[mt][i] = v;
        }
    if (r == 0) {
#pragma unroll
        for (int mt = 0; mt < 2; ++mt)
#pragma unroll
            for (int i = 0; i < 4; ++i) {
                int row = mgroup * BM + w * 32 + mt * 16 + g * 4 + i;
                partials[(size_t)ns * MM + row] = red[mt][i];
            }
    }
}

__global__ void finalize_kernel(const float* __restrict__ partials,
                                const float* __restrict__ bbias,
                                float* __restrict__ out) {
    int m = blockIdx.x * blockDim.x + threadIdx.x;
    if (m < MM) {
        float s = bbias[0];
#pragma unroll
        for (int c = 0; c < NSPLIT; ++c) s += partials[(size_t)c * MM + m];
        out[m] = s;
    }
}

extern "C" void kernel_launch(void* const* d_in, const int* in_sizes, int n_in,
                              void* d_out, int out_size, void* d_ws, size_t ws_size,
                              hipStream_t stream) {
    const float* xp    = (const float*)d_in[0];
    const float* X     = (const float*)d_in[1];
    const float* alpha = (const float*)d_in[2];
    const float* b     = (const float*)d_in[3];
    float* out = (float*)d_out;

    // ws: xbf 2MB | Xs 1MB | alpha4f 32KB | partials 8*16384*4 = 512KB
    unsigned short* xbf = (unsigned short*)d_ws;
    unsigned short* Xs  = xbf + (size_t)MM * DD;
    float* alpha4f = (float*)(Xs + (size_t)NN * DD);
    float* partials = alpha4f + NN;

    hipLaunchKernelGGL(convert_kernel, dim3(1280), dim3(256), 0, stream,
                       xp, X, alpha, xbf, Xs, alpha4f);

    hipLaunchKernelGGL(svr_main, dim3(128 * NSPLIT), dim3(256), 0, stream,
                       xbf, Xs, alpha4f, partials);

    hipLaunchKernelGGL(finalize_kernel, dim3(MM / 256), dim3(256), 0, stream,
                       partials, b, out);
}